// Round 20
// baseline (298.284 us; speedup 1.0000x reference)
//
#include <hip/hip_runtime.h>

#define B_  2
#define S_  2048
#define D_  1024
#define H_  16
#define DH_ 64

typedef _Float16 f16;
typedef f16   f16x2 __attribute__((ext_vector_type(2)));
typedef f16   f16x4 __attribute__((ext_vector_type(4)));
typedef f16   f16x8 __attribute__((ext_vector_type(8)));
typedef float f32x4 __attribute__((ext_vector_type(4)));
typedef float f32x16 __attribute__((ext_vector_type(16)));

static __device__ __forceinline__ f16x8 ldsm8(const f16* p) {
    return *reinterpret_cast<const f16x8*>(p);
}

// XOR swizzle for 128B-row LDS tiles (T2/G4).
static __device__ __forceinline__ int swz(int row, int byteInRow) {
    return row * 128 + (byteInRow ^ ((row & 7) << 4));
}

// async global->LDS DMA, 16B per lane; dest = wave-uniform base + lane*16
static __device__ __forceinline__ void gll16(const void* g, void* l) {
    __builtin_amdgcn_global_load_lds(
        (const __attribute__((address_space(1))) void*)g,
        (__attribute__((address_space(3))) void*)l, 16, 0, 0);
}

// pack two f32 -> one u32 of two f16 (RTZ), via the HW packed-convert
static __device__ __forceinline__ unsigned pk16(float a, float b) {
    return __builtin_bit_cast(unsigned, __builtin_amdgcn_cvt_pkrtz(a, b));
}

// ---------------------------------------------------------------------------
// Weight pre-convert kernels: fp32 [1024][1024] -> f16 (RTZ).
// cvt_w3: Wq,Wk,Wv -> dst (3 consecutive 1M-elem f16 matrices).  1536 blocks.
// cvt_w1: Wo -> dst.  512 blocks.
// ---------------------------------------------------------------------------
__global__ __launch_bounds__(256)
void cvt_w3(const float* __restrict__ Wq, const float* __restrict__ Wk,
            const float* __restrict__ Wv, f16* __restrict__ dst)
{
    size_t idx = ((size_t)blockIdx.x * 256 + threadIdx.x) * 8;
    int z = (int)(idx >> 20);
    size_t off = idx & 1048575;
    const float* W = z == 0 ? Wq : z == 1 ? Wk : Wv;
    float4 a = *reinterpret_cast<const float4*>(W + off);
    float4 b = *reinterpret_cast<const float4*>(W + off + 4);
    uint4 o = {pk16(a.x, a.y), pk16(a.z, a.w), pk16(b.x, b.y), pk16(b.z, b.w)};
    *reinterpret_cast<uint4*>(dst + idx) = o;
}

__global__ __launch_bounds__(256)
void cvt_w1(const float* __restrict__ Wo, f16* __restrict__ dst)
{
    size_t idx = ((size_t)blockIdx.x * 256 + threadIdx.x) * 8;
    float4 a = *reinterpret_cast<const float4*>(Wo + idx);
    float4 b = *reinterpret_cast<const float4*>(Wo + idx + 4);
    uint4 o = {pk16(a.x, a.y), pk16(a.z, a.w), pk16(b.x, b.y), pk16(b.z, b.w)};
    *reinterpret_cast<uint4*>(dst + idx) = o;
}

// ---------------------------------------------------------------------------
// Fused Q/K/V projection, BK=64.  A fp32 staged by threads (cvt to f16 in
// padded LDS); W pre-converted f16 staged via DMA (pre-swizzled source).
// blockIdx.z selects q/k/v.  OUT: z<2 f16 row-major (*scale for q), z=2
// f16 transposed-per-head.
// ---------------------------------------------------------------------------
__global__ __launch_bounds__(256)
void qkv_gemm(const float* __restrict__ Aq, const float* __restrict__ Ak,
              const float* __restrict__ Av, const f16* __restrict__ W16,
              const float* __restrict__ bq, const float* __restrict__ bk,
              const float* __restrict__ bv,
              f16* __restrict__ qo, f16* __restrict__ ko, f16* __restrict__ vo,
              float qscale)
{
    constexpr int K = 1024, N = 1024;
    __shared__ __align__(16) f16 As[128][72];      // padded fp32->f16 staging
    __shared__ __align__(16) f16 Bs[128 * 64];     // DMA-staged, swizzled
    const int z = blockIdx.z;
    const float* A    = z == 0 ? Aq : z == 1 ? Ak : Av;
    const f16*   W    = W16 + (size_t)z * 1024 * 1024;
    const float* bias = z == 0 ? bq : z == 1 ? bk : bv;
    const float scale = z == 0 ? qscale : 1.0f;

    const int t  = threadIdx.x;
    const int bm = blockIdx.y * 128;
    const int bn = blockIdx.x * 128;
    const int w  = t >> 6, l = t & 63;
    const int wr = w >> 1, wc = w & 1;
    const int lr = l & 15, lg = l >> 4;
    const int r8 = l >> 3, l8 = l & 7;
    const int xorc8 = (l8 ^ r8) * 8;

    f32x4 acc[4][4];
    #pragma unroll
    for (int m = 0; m < 4; ++m)
        #pragma unroll
        for (int n = 0; n < 4; ++n)
            acc[m][n] = (f32x4){0.f, 0.f, 0.f, 0.f};

    for (int km = 0; km < K / 64; ++km) {
        // W tile via DMA (4 ops/wave), A tile via loads+cvt
        #pragma unroll
        for (int i = 0; i < 4; ++i) {
            int rr = w * 32 + i * 8 + r8;
            gll16(W + (size_t)(bn + rr) * K + km * 64 + xorc8,
                  (char*)Bs + w * 4096 + i * 1024);
        }
        #pragma unroll
        for (int i = 0; i < 8; ++i) {
            int f = t + i * 256;
            int row = f >> 4, c4 = (f & 15) * 4;
            float4 v = *reinterpret_cast<const float4*>(A + (size_t)(bm + row) * K + km * 64 + c4);
            uint2 hv = {pk16(v.x, v.y), pk16(v.z, v.w)};
            *reinterpret_cast<uint2*>(&As[row][c4]) = hv;
        }
        asm volatile("s_waitcnt vmcnt(0) lgkmcnt(0)" ::: "memory");
        __builtin_amdgcn_s_barrier();

        #pragma unroll
        for (int kk = 0; kk < 2; ++kk) {
            f16x8 af[4], bfv[4];
            #pragma unroll
            for (int m = 0; m < 4; ++m)
                af[m] = ldsm8(&As[wr * 64 + m * 16 + lr][kk * 32 + lg * 8]);
            #pragma unroll
            for (int n = 0; n < 4; ++n)
                bfv[n] = *reinterpret_cast<const f16x8*>(
                    (const char*)Bs + swz(wc * 64 + n * 16 + lr, kk * 64 + lg * 16));
            #pragma unroll
            for (int m = 0; m < 4; ++m)
                #pragma unroll
                for (int n = 0; n < 4; ++n)
                    acc[m][n] = __builtin_amdgcn_mfma_f32_16x16x32_f16(af[m], bfv[n], acc[m][n], 0, 0, 0);
        }
        __syncthreads();
    }

    #pragma unroll
    for (int m = 0; m < 4; ++m) {
        #pragma unroll
        for (int n = 0; n < 4; ++n) {
            int col = bn + wc * 64 + n * 16 + lr;
            float bb = bias[col];
            if (z == 2) {
                int row0 = bm + wr * 64 + m * 16 + lg * 4;
                int b = row0 >> 11, s = row0 & 2047;
                int hh_ = col >> 6, d = col & 63;
                alignas(8) f16 hv[4];
                #pragma unroll
                for (int j = 0; j < 4; ++j)
                    hv[j] = (f16)(acc[m][n][j] + bb);
                *reinterpret_cast<uint2*>(vo +
                    (((size_t)(b * 16 + hh_) * 64 + d) * 2048 + s)) =
                    *reinterpret_cast<uint2*>(hv);
            } else {
                f16* Cp = z == 0 ? qo : ko;
                #pragma unroll
                for (int j = 0; j < 4; ++j) {
                    int row = bm + wr * 64 + m * 16 + lg * 4 + j;
                    Cp[(size_t)row * N + col] = (f16)((acc[m][n][j] + bb) * scale);
                }
            }
        }
    }
}

// C[M,N] = A[M,K] @ W[N,K]^T + bias.  A f16 (ctx), W16 f16: BOTH DMA-staged.
__global__ __launch_bounds__(256)
void gemm_out(const f16* __restrict__ A, const f16* __restrict__ W16,
              const float* __restrict__ bias, float* __restrict__ Cp)
{
    constexpr int K = 1024, N = 1024;
    __shared__ __align__(16) f16 As[128 * 64];
    __shared__ __align__(16) f16 Bs[128 * 64];
    const int t  = threadIdx.x;
    const int bm = blockIdx.y * 128;
    const int bn = blockIdx.x * 128;
    const int w  = t >> 6, l = t & 63;
    const int wr = w >> 1, wc = w & 1;
    const int lr = l & 15, lg = l >> 4;
    const int r8 = l >> 3, l8 = l & 7;
    const int xorc8 = (l8 ^ r8) * 8;

    f32x4 acc[4][4];
    #pragma unroll
    for (int m = 0; m < 4; ++m)
        #pragma unroll
        for (int n = 0; n < 4; ++n)
            acc[m][n] = (f32x4){0.f, 0.f, 0.f, 0.f};

    for (int km = 0; km < K / 64; ++km) {
        #pragma unroll
        for (int i = 0; i < 4; ++i) {
            int rr = w * 32 + i * 8 + r8;
            gll16(A + (size_t)(bm + rr) * K + km * 64 + xorc8,
                  (char*)As + w * 4096 + i * 1024);
            gll16(W16 + (size_t)(bn + rr) * K + km * 64 + xorc8,
                  (char*)Bs + w * 4096 + i * 1024);
        }
        asm volatile("s_waitcnt vmcnt(0)" ::: "memory");
        __builtin_amdgcn_s_barrier();

        #pragma unroll
        for (int kk = 0; kk < 2; ++kk) {
            f16x8 af[4], bfv[4];
            #pragma unroll
            for (int m = 0; m < 4; ++m)
                af[m] = *reinterpret_cast<const f16x8*>(
                    (const char*)As + swz(wr * 64 + m * 16 + lr, kk * 64 + lg * 16));
            #pragma unroll
            for (int n = 0; n < 4; ++n)
                bfv[n] = *reinterpret_cast<const f16x8*>(
                    (const char*)Bs + swz(wc * 64 + n * 16 + lr, kk * 64 + lg * 16));
            #pragma unroll
            for (int m = 0; m < 4; ++m)
                #pragma unroll
                for (int n = 0; n < 4; ++n)
                    acc[m][n] = __builtin_amdgcn_mfma_f32_16x16x32_f16(af[m], bfv[n], acc[m][n], 0, 0, 0);
        }
        __syncthreads();
    }

    #pragma unroll
    for (int m = 0; m < 4; ++m) {
        #pragma unroll
        for (int n = 0; n < 4; ++n) {
            int col = bn + wc * 64 + n * 16 + lr;
            float bb = bias[col];
            #pragma unroll
            for (int j = 0; j < 4; ++j) {
                int row = bm + wr * 64 + m * 16 + lg * 4 + j;
                Cp[(size_t)row * N + col] = acc[m][n][j] + bb;
            }
        }
    }
}

// ---------------------------------------------------------------------------
// Fused two-pass attention (R19 structure) + T5 setprio around MFMA chains.
// ---------------------------------------------------------------------------
__global__ __launch_bounds__(256, 3)
void attn_fused(const f16* __restrict__ qh, const f16* __restrict__ khp,
                const f16* __restrict__ vtg, const int* __restrict__ kmask,
                float* __restrict__ attn_out, f16* __restrict__ ch)
{
    __shared__ __align__(16) f16 ksd[2][64 * 64];
    __shared__ __align__(16) f16 vsd[2][64 * 64];
    __shared__ __align__(16) f16 ps[128][76];
    __shared__ float linv_s[128];
    __shared__ unsigned mbits[64];

    const int t  = threadIdx.x;
    const int w  = t >> 6, l = t & 63, lo = l & 31, hi = l >> 5;
    const bool H1 = (hi == 1);

    const int bid  = blockIdx.x;
    const int xcd  = bid & 7;
    const int slot = bid >> 3;
    const int bh   = (xcd << 2) | (slot >> 4);
    const int qt   = slot & 15;
    const int b    = bh >> 4;
    const int h    = bh & 15;
    const int q0   = qt * 128;
    const int row  = q0 + w * 32 + lo;
    const int lrow = w * 32 + lo;

    f16x8 qf[4];
    {
        const f16* qb = qh + (size_t)(b * S_ + row) * D_ + h * DH_ + hi * 8;
        #pragma unroll
        for (int c = 0; c < 4; ++c) qf[c] = *reinterpret_cast<const f16x8*>(qb + c * 16);
    }

    #pragma unroll
    for (int r = 0; r < 8; ++r) {
        int ktm = w * 8 + r;
        int mkv = kmask[b * S_ + ktm * 64 + l];
        unsigned long long bl = __ballot(mkv != 0);
        if (l == 0) {
            mbits[ktm * 2]     = (unsigned)bl;
            mbits[ktm * 2 + 1] = (unsigned)(bl >> 32);
        }
    }
    asm volatile("s_waitcnt vmcnt(0)" ::: "memory");

    const int r8 = l >> 3, l8 = l & 7;
    const int xorc8 = (l8 ^ r8) * 8;
    const f16* kgb = khp + (size_t)b * S_ * D_ + h * DH_;
    const f16* vgb = vtg + (size_t)(bh * 64) * S_;

    auto stageK128 = [&](int slot2, int jt) {
        char* tb = slot2 ? (char*)&vsd[0][0] : (char*)&ksd[0][0];
        #pragma unroll
        for (int i = 0; i < 4; ++i) {
            int rr = w * 32 + i * 8 + r8;
            gll16(kgb + (size_t)(jt * 128 + rr) * D_ + xorc8,
                  tb + w * 4096 + i * 1024);
        }
    };
    auto stageK = [&](int buf, int kt) {
        #pragma unroll
        for (int i = 0; i < 2; ++i) {
            int rr = i * 32 + w * 8 + r8;
            gll16(kgb + (size_t)(kt * 64 + rr) * D_ + xorc8,
                  (char*)ksd + buf * 8192 + i * 4096 + w * 1024);
        }
    };
    auto stageV = [&](int buf, int kt) {
        #pragma unroll
        for (int i = 0; i < 2; ++i) {
            int rr = i * 32 + w * 8 + r8;
            gll16(vgb + (size_t)rr * S_ + kt * 64 + xorc8,
                  (char*)vsd + buf * 8192 + i * 4096 + w * 1024);
        }
    };

    // ================= pass 1: row denominators (128-wide tiles) =================
    stageK128(0, 0);
    asm volatile("s_waitcnt vmcnt(0) lgkmcnt(0)" ::: "memory");
    __builtin_amdgcn_s_barrier();

    float ls0 = 0.f, ls1 = 0.f;
    for (int jt = 0; jt < 16; ++jt) {
        if (jt + 1 < 16) stageK128((jt + 1) & 1, jt + 1);
        const char* tb = (jt & 1) ? (const char*)&vsd[0][0] : (const char*)&ksd[0][0];

        #pragma unroll
        for (int h4 = 0; h4 < 4; ++h4) {
            f32x16 s;
            #pragma unroll
            for (int i = 0; i < 16; ++i) s[i] = 0.f;
            __builtin_amdgcn_s_setprio(1);
            #pragma unroll
            for (int c = 0; c < 4; ++c) {
                f16x8 kf = *reinterpret_cast<const f16x8*>(
                    tb + swz(h4 * 32 + lo, c * 32 + hi * 16));
                s = __builtin_amdgcn_mfma_f32_32x32x16_f16(kf, qf[c], s, 0, 0, 0);
            }
            __builtin_amdgcn_s_setprio(0);
            const unsigned m = mbits[jt * 4 + h4] >> (hi * 4);
            #pragma unroll
            for (int q4 = 0; q4 < 4; ++q4)
                #pragma unroll
                for (int j = 0; j < 4; ++j) {
                    float e = __builtin_amdgcn_exp2f(s[q4 * 4 + j]);
                    float z = ((m >> (q4 * 8 + j)) & 1) ? e : 0.0f;
                    if (q4 & 1) ls1 += z; else ls0 += z;
                }
        }
        asm volatile("s_waitcnt vmcnt(0)" ::: "memory");
        __builtin_amdgcn_s_barrier();
    }

    float ls = ls0 + ls1;
    ls += __shfl_xor(ls, 32, 64);
    const float invl = 1.0f / ls;
    if (hi == 0) linv_s[lrow] = invl;

    // ================= pass 2: attn write (LDS bounce) + PV =================
    stageK(0, 0); stageV(0, 0);
    asm volatile("s_waitcnt vmcnt(0) lgkmcnt(0)" ::: "memory");
    __builtin_amdgcn_s_barrier();

    f32x16 oc0, oc1;
    #pragma unroll
    for (int i = 0; i < 16; ++i) { oc0[i] = 0.f; oc1[i] = 0.f; }

    const int rseg  = t & 15;
    const int rrow0 = t >> 4;
    float* abase = attn_out + ((size_t)bh * S_ + q0) * S_;

    for (int kt = 0; kt < 32; ++kt) {
        if (kt + 1 < 32) {
            stageK((kt + 1) & 1, kt + 1);
            stageV((kt + 1) & 1, kt + 1);
        }
        const int cur = kt & 1;

        #pragma unroll
        for (int h2 = 0; h2 < 2; ++h2) {
            f32x16 s;
            #pragma unroll
            for (int i = 0; i < 16; ++i) s[i] = 0.f;
            __builtin_amdgcn_s_setprio(1);
            #pragma unroll
            for (int c = 0; c < 4; ++c) {
                f16x8 kf = *reinterpret_cast<const f16x8*>(
                    (const char*)ksd + cur * 8192 + swz(lo + h2 * 32, c * 32 + hi * 16));
                s = __builtin_amdgcn_mfma_f32_32x32x16_f16(kf, qf[c], s, 0, 0, 0);
            }
            __builtin_amdgcn_s_setprio(0);

            const unsigned m = mbits[kt * 2 + h2] >> (hi * 4);
            float p[16];
            #pragma unroll
            for (int q4 = 0; q4 < 4; ++q4)
                #pragma unroll
                for (int j = 0; j < 4; ++j) {
                    float e = __builtin_amdgcn_exp2f(s[q4 * 4 + j]);
                    p[q4 * 4 + j] = ((m >> (q4 * 8 + j)) & 1) ? e : 0.0f;
                }

            unsigned wa4[4], wb4[4];
            #pragma unroll
            for (int q4 = 0; q4 < 4; ++q4) {
                wa4[q4] = pk16(p[q4 * 4 + 0], p[q4 * 4 + 1]);
                wb4[q4] = pk16(p[q4 * 4 + 2], p[q4 * 4 + 3]);
                uint2 ww = {wa4[q4], wb4[q4]};
                *reinterpret_cast<uint2*>(&ps[lrow][h2 * 32 + q4 * 8 + hi * 4]) = ww;
            }

            #pragma unroll
            for (int cc = 0; cc < 2; ++cc) {
                const int c2 = h2 * 2 + cc, base = cc * 2;
                unsigned a0 = wa4[base], a1 = wa4[base + 1];
                unsigned b0 = wb4[base], b1 = wb4[base + 1];
                unsigned sa = H1 ? a0 : a1;
                unsigned sb = H1 ? b0 : b1;
                unsigned ra = (unsigned)__shfl_xor((int)sa, 32, 64);
                unsigned rb = (unsigned)__shfl_xor((int)sb, 32, 64);
                unsigned oa = H1 ? a1 : a0;
                unsigned ob = H1 ? b1 : b0;
                uint4 bw = H1 ? (uint4){ra, rb, oa, ob} : (uint4){oa, ob, ra, rb};
                f16x8 pf = __builtin_bit_cast(f16x8, bw);

                f16x8 va0 = *reinterpret_cast<const f16x8*>(
                    (const char*)vsd + cur * 8192 + swz(lo, c2 * 32 + hi * 16));
                f16x8 va1 = *reinterpret_cast<const f16x8*>(
                    (const char*)vsd + cur * 8192 + swz(lo + 32, c2 * 32 + hi * 16));
                __builtin_amdgcn_s_setprio(1);
                oc0 = __builtin_amdgcn_mfma_f32_32x32x16_f16(va0, pf, oc0, 0, 0, 0);
                oc1 = __builtin_amdgcn_mfma_f32_32x32x16_f16(va1, pf, oc1, 0, 0, 0);
                __builtin_amdgcn_s_setprio(0);
            }
        }

        asm volatile("s_waitcnt lgkmcnt(0)" ::: "memory");
        __builtin_amdgcn_s_barrier();

        #pragma unroll
        for (int ri = 0; ri < 8; ++ri) {
            int rr = ri * 16 + rrow0;
            f16x4 pv = *reinterpret_cast<const f16x4*>(&ps[rr][rseg * 4]);
            float li = linv_s[rr];
            f32x4 o = {(float)pv[0] * li, (float)pv[1] * li,
                       (float)pv[2] * li, (float)pv[3] * li};
            *reinterpret_cast<f32x4*>(abase + (size_t)rr * S_ + kt * 64 + rseg * 4) = o;
        }

        asm volatile("s_waitcnt vmcnt(8) lgkmcnt(0)" ::: "memory");
        __builtin_amdgcn_s_barrier();
    }

    f16* cb = ch + (size_t)(b * S_ + row) * D_ + h * DH_;
    #pragma unroll
    for (int q4 = 0; q4 < 4; ++q4) {
        int d0 = 8 * q4 + 4 * hi;
        f16x4 v0 = {(f16)(oc0[4 * q4 + 0] * invl), (f16)(oc0[4 * q4 + 1] * invl),
                    (f16)(oc0[4 * q4 + 2] * invl), (f16)(oc0[4 * q4 + 3] * invl)};
        *reinterpret_cast<f16x4*>(cb + d0) = v0;
        f16x4 v1 = {(f16)(oc1[4 * q4 + 0] * invl), (f16)(oc1[4 * q4 + 1] * invl),
                    (f16)(oc1[4 * q4 + 2] * invl), (f16)(oc1[4 * q4 + 3] * invl)};
        *reinterpret_cast<f16x4*>(cb + 32 + d0) = v1;
    }
}

extern "C" void kernel_launch(void* const* d_in, const int* in_sizes, int n_in,
                              void* d_out, int out_size, void* d_ws, size_t ws_size,
                              hipStream_t stream) {
    const float* query = (const float*)d_in[0];
    const float* key   = (const float*)d_in[1];
    const float* value = (const float*)d_in[2];
    const int*   kmask = (const int*)d_in[3];
    const float* Wq = (const float*)d_in[4];
    const float* bq = (const float*)d_in[5];
    const float* Wk = (const float*)d_in[6];
    const float* bk = (const float*)d_in[7];
    const float* Wv = (const float*)d_in[8];
    const float* bv = (const float*)d_in[9];
    const float* Wo = (const float*)d_in[10];
    const float* bo = (const float*)d_in[11];

    float* out  = (float*)d_out;
    float* attn = out + (size_t)B_ * S_ * D_;

    const size_t NE = (size_t)B_ * S_ * D_;   // 4M elements
    f16* qhp = (f16*)d_ws;
    f16* khp = qhp + NE;
    f16* vtg = khp + NE;      // V^T per head; DEAD after attn -> reused for Wo16
    f16* chx = vtg + NE;      // ctx; region holds Wqkv16 BEFORE attn writes ctx

    f16* Wqkv16 = chx;        // 3 x 1M f16 = 6MB, dead once qkv_gemm finishes
    f16* Wo16   = vtg;        // 1M f16 = 2MB, written after attn consumes V^T

    const float qscale = 0.125f * 1.44269504088896340736f;   // (1/sqrt(DH)) * log2(e)

    cvt_w3<<<dim3(1536), 256, 0, stream>>>(Wq, Wk, Wv, Wqkv16);

    qkv_gemm<<<dim3(8, 32, 3), 256, 0, stream>>>(query, key, value, Wqkv16,
                                                 bq, bk, bv, qhp, khp, vtg, qscale);

    attn_fused<<<dim3(B_ * H_ * (S_ / 128)), 256, 0, stream>>>(qhp, khp, vtg, kmask,
                                                               attn, chx);

    cvt_w1<<<dim3(512), 256, 0, stream>>>(Wo, Wo16);

    gemm_out<<<dim3(8, 32), 256, 0, stream>>>(chx, Wo16, bo, out);
}

// Round 21
// 295.427 us; speedup vs baseline: 1.0097x; 1.0097x over previous
//
#include <hip/hip_runtime.h>

#define B_  2
#define S_  2048
#define D_  1024
#define H_  16
#define DH_ 64

typedef _Float16 f16;
typedef f16   f16x2 __attribute__((ext_vector_type(2)));
typedef f16   f16x4 __attribute__((ext_vector_type(4)));
typedef f16   f16x8 __attribute__((ext_vector_type(8)));
typedef float f32x4 __attribute__((ext_vector_type(4)));
typedef float f32x16 __attribute__((ext_vector_type(16)));

static __device__ __forceinline__ f16x8 ldsm8(const f16* p) {
    return *reinterpret_cast<const f16x8*>(p);
}

// XOR swizzle for 128B-row LDS tiles (T2/G4).
static __device__ __forceinline__ int swz(int row, int byteInRow) {
    return row * 128 + (byteInRow ^ ((row & 7) << 4));
}

// async global->LDS DMA, 16B per lane; dest = wave-uniform base + lane*16
static __device__ __forceinline__ void gll16(const void* g, void* l) {
    __builtin_amdgcn_global_load_lds(
        (const __attribute__((address_space(1))) void*)g,
        (__attribute__((address_space(3))) void*)l, 16, 0, 0);
}

// pack two f32 -> one u32 of two f16 (RTZ), via the HW packed-convert
static __device__ __forceinline__ unsigned pk16(float a, float b) {
    return __builtin_bit_cast(unsigned, __builtin_amdgcn_cvt_pkrtz(a, b));
}

// ---------------------------------------------------------------------------
// Fused Q/K/V projection: blockIdx.z selects which of the three GEMMs.
// (R19 version — reverted per pre-commit after R20's staging change was flat)
// ---------------------------------------------------------------------------
__global__ __launch_bounds__(256)
void qkv_gemm(const float* __restrict__ Aq, const float* __restrict__ Ak,
              const float* __restrict__ Av,
              const float* __restrict__ Wq, const float* __restrict__ Wk,
              const float* __restrict__ Wv,
              const float* __restrict__ bq, const float* __restrict__ bk,
              const float* __restrict__ bv,
              f16* __restrict__ qo, f16* __restrict__ ko, f16* __restrict__ vo,
              float qscale)
{
    constexpr int K = 1024, N = 1024;
    __shared__ __align__(16) f16 As[128][40];
    __shared__ __align__(16) f16 Bs[128][40];
    const int z = blockIdx.z;
    const float* A    = z == 0 ? Aq : z == 1 ? Ak : Av;
    const float* W    = z == 0 ? Wq : z == 1 ? Wk : Wv;
    const float* bias = z == 0 ? bq : z == 1 ? bk : bv;
    const float scale = z == 0 ? qscale : 1.0f;

    const int t  = threadIdx.x;
    const int bm = blockIdx.y * 128;
    const int bn = blockIdx.x * 128;
    const int w  = t >> 6, l = t & 63;
    const int wr = w >> 1, wc = w & 1;
    const int lr = l & 15, lg = l >> 4;

    f32x4 acc[4][4];
    #pragma unroll
    for (int m = 0; m < 4; ++m)
        #pragma unroll
        for (int n = 0; n < 4; ++n)
            acc[m][n] = (f32x4){0.f, 0.f, 0.f, 0.f};

    for (int kt = 0; kt < K / 32; ++kt) {
        #pragma unroll
        for (int i = 0; i < 4; ++i) {
            int idx = t + i * 256;
            int row = idx >> 3, g = idx & 7;
            float4 v = *reinterpret_cast<const float4*>(A + (size_t)(bm + row) * K + kt * 32 + g * 4);
            alignas(8) f16 hh[4] = {(f16)v.x, (f16)v.y, (f16)v.z, (f16)v.w};
            *reinterpret_cast<uint2*>(&As[row][g * 4]) = *reinterpret_cast<uint2*>(hh);
        }
        #pragma unroll
        for (int i = 0; i < 4; ++i) {
            int idx = t + i * 256;
            int row = idx >> 3, g = idx & 7;
            float4 v = *reinterpret_cast<const float4*>(W + (size_t)(bn + row) * K + kt * 32 + g * 4);
            alignas(8) f16 hh[4] = {(f16)v.x, (f16)v.y, (f16)v.z, (f16)v.w};
            *reinterpret_cast<uint2*>(&Bs[row][g * 4]) = *reinterpret_cast<uint2*>(hh);
        }
        __syncthreads();

        f16x8 af[4], bfv[4];
        #pragma unroll
        for (int m = 0; m < 4; ++m) af[m]  = ldsm8(&As[wr * 64 + m * 16 + lr][lg * 8]);
        #pragma unroll
        for (int n = 0; n < 4; ++n) bfv[n] = ldsm8(&Bs[wc * 64 + n * 16 + lr][lg * 8]);
        #pragma unroll
        for (int m = 0; m < 4; ++m)
            #pragma unroll
            for (int n = 0; n < 4; ++n)
                acc[m][n] = __builtin_amdgcn_mfma_f32_16x16x32_f16(af[m], bfv[n], acc[m][n], 0, 0, 0);
        __syncthreads();
    }

    #pragma unroll
    for (int m = 0; m < 4; ++m) {
        #pragma unroll
        for (int n = 0; n < 4; ++n) {
            int col = bn + wc * 64 + n * 16 + lr;
            float bb = bias[col];
            if (z == 2) {
                int row0 = bm + wr * 64 + m * 16 + lg * 4;
                int b = row0 >> 11, s = row0 & 2047;
                int hh_ = col >> 6, d = col & 63;
                alignas(8) f16 hv[4];
                #pragma unroll
                for (int j = 0; j < 4; ++j)
                    hv[j] = (f16)(acc[m][n][j] + bb);
                *reinterpret_cast<uint2*>(vo +
                    (((size_t)(b * 16 + hh_) * 64 + d) * 2048 + s)) =
                    *reinterpret_cast<uint2*>(hv);
            } else {
                f16* Cp = z == 0 ? qo : ko;
                #pragma unroll
                for (int j = 0; j < 4; ++j) {
                    int row = bm + wr * 64 + m * 16 + lg * 4 + j;
                    Cp[(size_t)row * N + col] = (f16)((acc[m][n][j] + bb) * scale);
                }
            }
        }
    }
}

// C[M,N] = A[M,K] @ W[N,K]^T (+bias).  A f16, out f32 (out-projection).
__global__ __launch_bounds__(256)
void gemm_out(const f16* __restrict__ A, const float* __restrict__ W,
              const float* __restrict__ bias, float* __restrict__ Cp)
{
    constexpr int K = 1024, N = 1024;
    __shared__ __align__(16) f16 As[128][40];
    __shared__ __align__(16) f16 Bs[128][40];
    const int t  = threadIdx.x;
    const int bm = blockIdx.y * 128;
    const int bn = blockIdx.x * 128;
    const int w  = t >> 6, l = t & 63;
    const int wr = w >> 1, wc = w & 1;
    const int lr = l & 15, lg = l >> 4;

    f32x4 acc[4][4];
    #pragma unroll
    for (int m = 0; m < 4; ++m)
        #pragma unroll
        for (int n = 0; n < 4; ++n)
            acc[m][n] = (f32x4){0.f, 0.f, 0.f, 0.f};

    for (int kt = 0; kt < K / 32; ++kt) {
        #pragma unroll
        for (int i = 0; i < 2; ++i) {
            int idx = t + i * 256;
            int row = idx >> 2, g = idx & 3;
            *reinterpret_cast<uint4*>(&As[row][g * 8]) =
                *reinterpret_cast<const uint4*>(A + (size_t)(bm + row) * K + kt * 32 + g * 8);
        }
        #pragma unroll
        for (int i = 0; i < 4; ++i) {
            int idx = t + i * 256;
            int row = idx >> 3, g = idx & 7;
            float4 v = *reinterpret_cast<const float4*>(W + (size_t)(bn + row) * K + kt * 32 + g * 4);
            alignas(8) f16 hh[4] = {(f16)v.x, (f16)v.y, (f16)v.z, (f16)v.w};
            *reinterpret_cast<uint2*>(&Bs[row][g * 4]) = *reinterpret_cast<uint2*>(hh);
        }
        __syncthreads();

        f16x8 af[4], bfv[4];
        #pragma unroll
        for (int m = 0; m < 4; ++m) af[m]  = ldsm8(&As[wr * 64 + m * 16 + lr][lg * 8]);
        #pragma unroll
        for (int n = 0; n < 4; ++n) bfv[n] = ldsm8(&Bs[wc * 64 + n * 16 + lr][lg * 8]);
        #pragma unroll
        for (int m = 0; m < 4; ++m)
            #pragma unroll
            for (int n = 0; n < 4; ++n)
                acc[m][n] = __builtin_amdgcn_mfma_f32_16x16x32_f16(af[m], bfv[n], acc[m][n], 0, 0, 0);
        __syncthreads();
    }

    #pragma unroll
    for (int m = 0; m < 4; ++m) {
        #pragma unroll
        for (int n = 0; n < 4; ++n) {
            int col = bn + wc * 64 + n * 16 + lr;
            float bb = bias[col];
            #pragma unroll
            for (int j = 0; j < 4; ++j) {
                int row = bm + wr * 64 + m * 16 + lg * 4 + j;
                Cp[(size_t)row * N + col] = acc[m][n][j] + bb;
            }
        }
    }
}

// ---------------------------------------------------------------------------
// Fused two-pass attention.  Pass 1: 128-wide K tiles (16 iterations).
// Pass 2: QK/exp/pack/ps-write phase -> barrier -> readback INTERLEAVED
// with the deferred PV MFMAs (P B-frag words carried in registers; vsd[cur]
// stays valid across the barrier) -> barrier.  The previously-serialized
// readback phase now hides under 16 PV MFMAs.
// ---------------------------------------------------------------------------
__global__ __launch_bounds__(256, 3)
void attn_fused(const f16* __restrict__ qh, const f16* __restrict__ khp,
                const f16* __restrict__ vtg, const int* __restrict__ kmask,
                float* __restrict__ attn_out, f16* __restrict__ ch)
{
    __shared__ __align__(16) f16 ksd[2][64 * 64];   // pass2: K dbuf; pass1: tile slot 0
    __shared__ __align__(16) f16 vsd[2][64 * 64];   // pass2: V^T dbuf; pass1: tile slot 1
    __shared__ __align__(16) f16 ps[128][76];       // P bounce
    __shared__ float linv_s[128];
    __shared__ unsigned mbits[64];

    const int t  = threadIdx.x;
    const int w  = t >> 6, l = t & 63, lo = l & 31, hi = l >> 5;
    const bool H1 = (hi == 1);

    // 512 blocks = 8 xcd * 4 bh * 16 qt
    const int bid  = blockIdx.x;
    const int xcd  = bid & 7;
    const int slot = bid >> 3;
    const int bh   = (xcd << 2) | (slot >> 4);
    const int qt   = slot & 15;
    const int b    = bh >> 4;
    const int h    = bh & 15;
    const int q0   = qt * 128;
    const int row  = q0 + w * 32 + lo;       // this lane's q-row
    const int lrow = w * 32 + lo;            // row within tile (0..127)

    // Q fragments (lane's row, full D=64)
    f16x8 qf[4];
    {
        const f16* qb = qh + (size_t)(b * S_ + row) * D_ + h * DH_ + hi * 8;
        #pragma unroll
        for (int c = 0; c < 4; ++c) qf[c] = *reinterpret_cast<const f16x8*>(qb + c * 16);
    }

    // mask bits via ballot (kmask loads happen here, pre-DMA)
    #pragma unroll
    for (int r = 0; r < 8; ++r) {
        int ktm = w * 8 + r;
        int mkv = kmask[b * S_ + ktm * 64 + l];
        unsigned long long bl = __ballot(mkv != 0);
        if (l == 0) {
            mbits[ktm * 2]     = (unsigned)bl;
            mbits[ktm * 2 + 1] = (unsigned)(bl >> 32);
        }
    }
    // drain all compiler-tracked vmem (qf, kmask) before first DMA issue
    asm volatile("s_waitcnt vmcnt(0)" ::: "memory");

    const int r8 = l >> 3, l8 = l & 7;
    const int xorc8 = (l8 ^ r8) * 8;          // pre-XORed source chunk
    const f16* kgb = khp + (size_t)b * S_ * D_ + h * DH_;
    const f16* vgb = vtg + (size_t)(bh * 64) * S_;

    auto stageK128 = [&](int slot2, int jt) {  // 4 vmem ops per wave
        char* tb = slot2 ? (char*)&vsd[0][0] : (char*)&ksd[0][0];
        #pragma unroll
        for (int i = 0; i < 4; ++i) {
            int rr = w * 32 + i * 8 + r8;
            gll16(kgb + (size_t)(jt * 128 + rr) * D_ + xorc8,
                  tb + w * 4096 + i * 1024);
        }
    };
    auto stageK = [&](int buf, int kt) {
        #pragma unroll
        for (int i = 0; i < 2; ++i) {
            int rr = i * 32 + w * 8 + r8;
            gll16(kgb + (size_t)(kt * 64 + rr) * D_ + xorc8,
                  (char*)ksd + buf * 8192 + i * 4096 + w * 1024);
        }
    };
    auto stageV = [&](int buf, int kt) {
        #pragma unroll
        for (int i = 0; i < 2; ++i) {
            int rr = i * 32 + w * 8 + r8;
            gll16(vgb + (size_t)rr * S_ + kt * 64 + xorc8,
                  (char*)vsd + buf * 8192 + i * 4096 + w * 1024);
        }
    };

    // ================= pass 1: row denominators (128-wide tiles) =================
    stageK128(0, 0);
    asm volatile("s_waitcnt vmcnt(0) lgkmcnt(0)" ::: "memory");
    __builtin_amdgcn_s_barrier();

    float ls0 = 0.f, ls1 = 0.f;
    for (int jt = 0; jt < 16; ++jt) {
        if (jt + 1 < 16) stageK128((jt + 1) & 1, jt + 1);
        const char* tb = (jt & 1) ? (const char*)&vsd[0][0] : (const char*)&ksd[0][0];

        #pragma unroll
        for (int h4 = 0; h4 < 4; ++h4) {
            f32x16 s;
            #pragma unroll
            for (int i = 0; i < 16; ++i) s[i] = 0.f;
            #pragma unroll
            for (int c = 0; c < 4; ++c) {
                f16x8 kf = *reinterpret_cast<const f16x8*>(
                    tb + swz(h4 * 32 + lo, c * 32 + hi * 16));
                s = __builtin_amdgcn_mfma_f32_32x32x16_f16(kf, qf[c], s, 0, 0, 0);
            }
            const unsigned m = mbits[jt * 4 + h4] >> (hi * 4);
            #pragma unroll
            for (int q4 = 0; q4 < 4; ++q4)
                #pragma unroll
                for (int j = 0; j < 4; ++j) {
                    float e = __builtin_amdgcn_exp2f(s[q4 * 4 + j]);
                    float z = ((m >> (q4 * 8 + j)) & 1) ? e : 0.0f;
                    if (q4 & 1) ls1 += z; else ls0 += z;
                }
        }
        asm volatile("s_waitcnt vmcnt(0)" ::: "memory");
        __builtin_amdgcn_s_barrier();
    }

    float ls = ls0 + ls1;
    ls += __shfl_xor(ls, 32, 64);
    const float invl = 1.0f / ls;
    if (hi == 0) linv_s[lrow] = invl;

    // ================= pass 2: attn write (LDS bounce) + deferred PV =================
    stageK(0, 0); stageV(0, 0);
    asm volatile("s_waitcnt vmcnt(0) lgkmcnt(0)" ::: "memory");
    __builtin_amdgcn_s_barrier();

    f32x16 oc0, oc1;
    #pragma unroll
    for (int i = 0; i < 16; ++i) { oc0[i] = 0.f; oc1[i] = 0.f; }

    const int rseg  = t & 15;
    const int rrow0 = t >> 4;
    float* abase = attn_out + ((size_t)bh * S_ + q0) * S_;

    for (int kt = 0; kt < 32; ++kt) {
        if (kt + 1 < 32) {
            stageK((kt + 1) & 1, kt + 1);
            stageV((kt + 1) & 1, kt + 1);
        }
        const int cur = kt & 1;

        // ---- phase A: QK^T, exp, pack, ps write; P B-frags -> registers ----
        uint4 pfw[4];
        #pragma unroll
        for (int h2 = 0; h2 < 2; ++h2) {
            f32x16 s;
            #pragma unroll
            for (int i = 0; i < 16; ++i) s[i] = 0.f;
            #pragma unroll
            for (int c = 0; c < 4; ++c) {
                f16x8 kf = *reinterpret_cast<const f16x8*>(
                    (const char*)ksd + cur * 8192 + swz(lo + h2 * 32, c * 32 + hi * 16));
                s = __builtin_amdgcn_mfma_f32_32x32x16_f16(kf, qf[c], s, 0, 0, 0);
            }

            const unsigned m = mbits[kt * 2 + h2] >> (hi * 4);
            float p[16];
            #pragma unroll
            for (int q4 = 0; q4 < 4; ++q4)
                #pragma unroll
                for (int j = 0; j < 4; ++j) {
                    float e = __builtin_amdgcn_exp2f(s[q4 * 4 + j]);
                    p[q4 * 4 + j] = ((m >> (q4 * 8 + j)) & 1) ? e : 0.0f;
                }

            unsigned wa4[4], wb4[4];
            #pragma unroll
            for (int q4 = 0; q4 < 4; ++q4) {
                wa4[q4] = pk16(p[q4 * 4 + 0], p[q4 * 4 + 1]);
                wb4[q4] = pk16(p[q4 * 4 + 2], p[q4 * 4 + 3]);
                uint2 ww = {wa4[q4], wb4[q4]};
                *reinterpret_cast<uint2*>(&ps[lrow][h2 * 32 + q4 * 8 + hi * 4]) = ww;
            }

            #pragma unroll
            for (int cc = 0; cc < 2; ++cc) {
                const int base = cc * 2;
                unsigned a0 = wa4[base], a1 = wa4[base + 1];
                unsigned b0 = wb4[base], b1 = wb4[base + 1];
                unsigned sa = H1 ? a0 : a1;
                unsigned sb = H1 ? b0 : b1;
                unsigned ra = (unsigned)__shfl_xor((int)sa, 32, 64);
                unsigned rb = (unsigned)__shfl_xor((int)sb, 32, 64);
                unsigned oa = H1 ? a1 : a0;
                unsigned ob = H1 ? b1 : b0;
                pfw[h2 * 2 + cc] = H1 ? (uint4){ra, rb, oa, ob} : (uint4){oa, ob, ra, rb};
            }
        }

        // ps complete across all waves (stores/DMA stay in flight)
        asm volatile("s_waitcnt lgkmcnt(0)" ::: "memory");
        __builtin_amdgcn_s_barrier();

        // ---- phase B: PV MFMAs interleaved with full-line readback ----
        #pragma unroll
        for (int c2 = 0; c2 < 4; ++c2) {
            f16x8 pf = __builtin_bit_cast(f16x8, pfw[c2]);
            f16x8 va0 = *reinterpret_cast<const f16x8*>(
                (const char*)vsd + cur * 8192 + swz(lo, c2 * 32 + hi * 16));
            f16x8 va1 = *reinterpret_cast<const f16x8*>(
                (const char*)vsd + cur * 8192 + swz(lo + 32, c2 * 32 + hi * 16));
            oc0 = __builtin_amdgcn_mfma_f32_32x32x16_f16(va0, pf, oc0, 0, 0, 0);
            oc1 = __builtin_amdgcn_mfma_f32_32x32x16_f16(va1, pf, oc1, 0, 0, 0);

            // two readback rows per c2 chunk (8 total), interleaved with MFMA
            #pragma unroll
            for (int ri = 0; ri < 2; ++ri) {
                int rr = (c2 * 2 + ri) * 16 + rrow0;
                f16x4 pv = *reinterpret_cast<const f16x4*>(&ps[rr][rseg * 4]);
                float li = linv_s[rr];
                f32x4 o = {(float)pv[0] * li, (float)pv[1] * li,
                           (float)pv[2] * li, (float)pv[3] * li};
                *reinterpret_cast<f32x4*>(abase + (size_t)rr * S_ + kt * 64 + rseg * 4) = o;
            }
        }

        // next tile's DMA (4 oldest) done; 8 stores stay in flight.
        // lgkmcnt(0): readback ds_reads done before ps is overwritten.
        asm volatile("s_waitcnt vmcnt(8) lgkmcnt(0)" ::: "memory");
        __builtin_amdgcn_s_barrier();
    }

    // ---- ctx store: lane owns its row ----
    f16* cb = ch + (size_t)(b * S_ + row) * D_ + h * DH_;
    #pragma unroll
    for (int q4 = 0; q4 < 4; ++q4) {
        int d0 = 8 * q4 + 4 * hi;
        f16x4 v0 = {(f16)(oc0[4 * q4 + 0] * invl), (f16)(oc0[4 * q4 + 1] * invl),
                    (f16)(oc0[4 * q4 + 2] * invl), (f16)(oc0[4 * q4 + 3] * invl)};
        *reinterpret_cast<f16x4*>(cb + d0) = v0;
        f16x4 v1 = {(f16)(oc1[4 * q4 + 0] * invl), (f16)(oc1[4 * q4 + 1] * invl),
                    (f16)(oc1[4 * q4 + 2] * invl), (f16)(oc1[4 * q4 + 3] * invl)};
        *reinterpret_cast<f16x4*>(cb + 32 + d0) = v1;
    }
}

extern "C" void kernel_launch(void* const* d_in, const int* in_sizes, int n_in,
                              void* d_out, int out_size, void* d_ws, size_t ws_size,
                              hipStream_t stream) {
    const float* query = (const float*)d_in[0];
    const float* key   = (const float*)d_in[1];
    const float* value = (const float*)d_in[2];
    const int*   kmask = (const int*)d_in[3];
    const float* Wq = (const float*)d_in[4];
    const float* bq = (const float*)d_in[5];
    const float* Wk = (const float*)d_in[6];
    const float* bk = (const float*)d_in[7];
    const float* Wv = (const float*)d_in[8];
    const float* bv = (const float*)d_in[9];
    const float* Wo = (const float*)d_in[10];
    const float* bo = (const float*)d_in[11];

    float* out  = (float*)d_out;
    float* attn = out + (size_t)B_ * S_ * D_;

    const size_t NE = (size_t)B_ * S_ * D_;
    f16* qhp = (f16*)d_ws;
    f16* khp = qhp + NE;
    f16* vtg = khp + NE;             // per-head transposed V: [(b*16+h)*64+d][s]
    f16* chx = vtg + NE;             // 32 MB of ws total

    const float qscale = 0.125f * 1.44269504088896340736f;   // (1/sqrt(DH)) * log2(e)

    qkv_gemm<<<dim3(8, 32, 3), 256, 0, stream>>>(query, key, value, Wq, Wk, Wv,
                                                 bq, bk, bv, qhp, khp, vtg, qscale);

    attn_fused<<<dim3(B_ * H_ * (S_ / 128)), 256, 0, stream>>>(qhp, khp, vtg, kmask,
                                                               attn, chx);

    gemm_out<<<dim3(8, 32), 256, 0, stream>>>(chx, Wo, bo, out);
}